// Round 4
// baseline (442.423 us; speedup 1.0000x reference)
//
#include <hip/hip_runtime.h>
#include <hip/hip_bf16.h>
#include <cstdint>
#include <cstddef>

// Problem constants
#define B_SZ 4096
#define T_SZ 4
#define C_SZ 1024
#define H_SZ 8
#define DH_SZ 128
#define NQKV 3072                      // 3*C
#define SCALE_F 0.08838834764831845f   // 128^-0.5

typedef float f32x4 __attribute__((ext_vector_type(4)));
typedef short s16x8 __attribute__((ext_vector_type(8)));

static __device__ __forceinline__ float bf2f(unsigned short u) {
    union { unsigned int i; float f; } x; x.i = ((unsigned int)u) << 16; return x.f;
}
static __device__ __forceinline__ unsigned short f2bf(float f) {
    union { unsigned int i; float f; } x; x.f = f;
    unsigned int r = x.i + 0x7FFFu + ((x.i >> 16) & 1u);   // RNE
    return (unsigned short)(r >> 16);
}

// async global->LDS, 16B per lane; lds base must be wave-uniform (HW adds lane*16)
typedef const __attribute__((address_space(1))) void* gas_ptr;
typedef __attribute__((address_space(3))) void* las_ptr;
static __device__ __forceinline__ void async16(const void* g, void* l) {
    __builtin_amdgcn_global_load_lds((gas_ptr)g, (las_ptr)l, 16, 0, 0);
}

// ---------------- elementwise fp32 -> bf16 ----------------
__global__ __launch_bounds__(256) void cvt_f32_bf16(const float* __restrict__ src,
                                                    unsigned short* __restrict__ dst, int n4) {
    int i = blockIdx.x * 256 + threadIdx.x;
    if (i >= n4) return;
    float4 v = reinterpret_cast<const float4*>(src)[i];
    ushort4 o;
    o.x = f2bf(v.x); o.y = f2bf(v.y); o.z = f2bf(v.z); o.w = f2bf(v.w);
    reinterpret_cast<ushort4*>(dst)[i] = o;
}

// ---------------- transpose + convert: src[K][N] fp32 -> dst[N][K] bf16 (per z=task) --------
__global__ __launch_bounds__(256) void transpose_cvt(const float* __restrict__ src,
                                                     unsigned short* __restrict__ dst,
                                                     int K, int N) {
    __shared__ float tile[32][33];
    const float* s = src + (size_t)blockIdx.z * K * N;
    unsigned short* d = dst + (size_t)blockIdx.z * K * N;
    int n0 = blockIdx.x * 32, k0 = blockIdx.y * 32;
    int tx = threadIdx.x, ty = threadIdx.y;
#pragma unroll
    for (int i = 0; i < 4; i++) {
        int k = k0 + ty + i * 8;
        tile[ty + i * 8][tx] = s[(size_t)k * N + n0 + tx];
    }
    __syncthreads();
#pragma unroll
    for (int i = 0; i < 4; i++) {
        int n = n0 + ty + i * 8;
        d[(size_t)n * K + k0 + tx] = f2bf(tile[tx][ty + i * 8]);
    }
}

// ---------------- 256x256 pipelined bf16 MFMA GEMM (round 4) ----------------
// A: bf16, row m of task t at A + t*C + m*(T*C), K = C = 1024
// Bt: bf16 [T][NSIZE][K] (B transposed), bias: fp32 [T][NSIZE]
//
// ROUND-4: one-phase-ahead fragment reads. MFMA quadrant order per tile:
//   P0:(A0,B0) P1:(A1,B0) P2:(A1,B1) P3:(A0,B1)  — one operand changes per phase.
// Reads issued one phase early (8/4/8/4 per phase), consumed next phase; compiler
// inserts counted lgkm waits (all deps in its model) -> LDS reads overlap MFMA.
// A-frag double buffer X/Y with per-tile role swap: even kt: A0->X,A1->Y; odd: swap.
// B0/B1 single-buffered (2-region write-use gaps).
// Staging per tile: P0: Ah1(kt+1)->buf^1 [2]; P2: B0(kt+2)->buf [2];
//                   P3: Ah0(kt+2),B1(kt+2)->buf [4].
// Waits: single all-waves vmcnt(0) at P2 entry + barrier (covers Ah1(kt+1) staged
// at kt.P0 and read at kt.P2 by wm=1 waves; everything older a fortiori).
// Overwrite ledger (all >=2 barriers after readers' lgkm retirement):
//   Ah1(kt+1)@P0 into buf^1: last reads kt-1.P0 (retired < kt-1.P1 bar)  OK
//   B0(kt+2)@P2 into buf:   last reads kt-1.P3 (retired < kt.P1 bar)     OK
//   Ah0(kt+2)@P3 into buf:  last reads kt.P0   (retired < kt.P2 bar)     OK
//   B1(kt+2)@P3 into buf:   last reads kt.P1   (retired < kt.P3 bar)     OK
template<int NSIZE, int EPI>
__global__ __launch_bounds__(512, 1) void gemm256(
    const unsigned short* __restrict__ A,
    const unsigned short* __restrict__ Bt,
    const float* __restrict__ bias,
    const float* __restrict__ resid,
    unsigned short* __restrict__ out_bf,
    float* __restrict__ out_f)
{
    constexpr int BK  = 64;
    constexpr int NBX = NSIZE / 256;   // 12 (qkv) or 4 (proj)
    constexpr int NBY = B_SZ / 256;    // 16
    constexpr int NWG = NBX * NBY * T_SZ;   // 768 / 256, both % 8 == 0

    __shared__ __align__(16) unsigned short lds[65536];   // 128 KiB
    // A buf0 [0,16384) buf1 [16384,32768); B buf0 [32768,49152) buf1 [49152,65536)
    // within buf: half0 [0,8192), half1 [8192,16384); row stride 64 ushorts

    // XCD-aware swizzle (T1)
    const int bid = blockIdx.x;
    const int swz = (bid & 7) * (NWG >> 3) + (bid >> 3);
    const int by  = swz & (NBY - 1);
    const int tmp = swz >> 4;
    const int bx  = tmp % NBX;
    const int t   = tmp / NBX;
    const int m0  = by * 256;
    const int n0  = bx * 256;

    const int tid  = threadIdx.x;
    const int lane = tid & 63;
    const int w    = tid >> 6;
    const int wm   = w >> 2;        // 0..1: which 128-row A half
    const int wn   = w & 3;         // 0..3: which 64-col B slice
    const int quad = lane >> 4;
    const int l16  = lane & 15;

    // ---- staging slot precompute (2 insts/thread per half-tile) ----
    // slot q = (w*2+i)*64 + lane; row = q>>3; stored chunk = q&7;
    // fetched data chunk = (q&7) ^ (row&7)  (inverse-swizzled global source)
    const int q0  = w * 128 + lane;
    const int q1  = q0 + 64;
    const int r0  = q0 >> 3, ch0 = (q0 & 7) ^ (r0 & 7);
    const int r1  = q1 >> 3, ch1 = (q1 & 7) ^ (r1 & 7);
    const unsigned short* Abase = A + (size_t)t * C_SZ;
    const unsigned short* Bbase = Bt + (size_t)t * NSIZE * C_SZ;
    const unsigned short* gA0 = Abase + (size_t)(m0 + r0) * (T_SZ * C_SZ) + ch0 * 8;
    const unsigned short* gA1 = Abase + (size_t)(m0 + r1) * (T_SZ * C_SZ) + ch1 * 8;
    const unsigned short* gB0 = Bbase + (size_t)(n0 + r0) * C_SZ + ch0 * 8;
    const unsigned short* gB1 = Bbase + (size_t)(n0 + r1) * C_SZ + ch1 * 8;
    unsigned short* dA0 = &lds[(w * 2 + 0) * 512];          // wave-uniform bases
    unsigned short* dA1 = &lds[(w * 2 + 1) * 512];
    unsigned short* dB0 = &lds[32768 + (w * 2 + 0) * 512];
    unsigned short* dB1 = &lds[32768 + (w * 2 + 1) * 512];

#define STG_A(buf, h, kt) do { \
    async16(gA0 + (size_t)(h) * 128 * (T_SZ * C_SZ) + (kt) * BK, dA0 + (buf) * 16384 + (h) * 8192); \
    async16(gA1 + (size_t)(h) * 128 * (T_SZ * C_SZ) + (kt) * BK, dA1 + (buf) * 16384 + (h) * 8192); \
} while (0)
#define STG_B(buf, h, kt) do { \
    async16(gB0 + (size_t)(h) * 128 * C_SZ + (kt) * BK, dB0 + (buf) * 16384 + (h) * 8192); \
    async16(gB1 + (size_t)(h) * 128 * C_SZ + (kt) * BK, dB1 + (buf) * 16384 + (h) * 8192); \
} while (0)

    // ---- fragment read bases; chunk swizzle: stored = (ks*4+quad) ^ (l16&7) ----
    const int s7   = l16 & 7;
    const int swk0 = ((0 * 4 + quad) ^ s7) * 8;
    const int swk1 = ((1 * 4 + quad) ^ s7) * 8;
    const unsigned short* aR = &lds[wm * 8192 + l16 * 64];
    const unsigned short* bR = &lds[32768 + (wn >> 1) * 8192 + ((wn & 1) * 64 + l16) * 64];

#define LD_An(bufi, mh, DST) do { \
    _Pragma("unroll") \
    for (int mi = 0; mi < 4; ++mi) { \
        DST[mi][0] = *(const s16x8*)(aR + (bufi) * 16384 + ((mh) * 4 + mi) * 1024 + swk0); \
        DST[mi][1] = *(const s16x8*)(aR + (bufi) * 16384 + ((mh) * 4 + mi) * 1024 + swk1); \
    } \
} while (0)
#define LD_Bn(bufi, nh, DST) do { \
    _Pragma("unroll") \
    for (int ni = 0; ni < 2; ++ni) { \
        DST[ni][0] = *(const s16x8*)(bR + (bufi) * 16384 + ((nh) * 2 + ni) * 1024 + swk0); \
        DST[ni][1] = *(const s16x8*)(bR + (bufi) * 16384 + ((nh) * 2 + ni) * 1024 + swk1); \
    } \
} while (0)
#define MMn(AARR, mh, nh, BARR) do { \
    _Pragma("unroll") \
    for (int mi = 0; mi < 4; ++mi) \
    _Pragma("unroll") \
    for (int ni = 0; ni < 2; ++ni) { \
        acc[(mh) * 4 + mi][(nh) * 2 + ni] = __builtin_amdgcn_mfma_f32_16x16x32_bf16( \
            AARR[mi][0], BARR[ni][0], acc[(mh) * 4 + mi][(nh) * 2 + ni], 0, 0, 0); \
        acc[(mh) * 4 + mi][(nh) * 2 + ni] = __builtin_amdgcn_mfma_f32_16x16x32_bf16( \
            AARR[mi][1], BARR[ni][1], acc[(mh) * 4 + mi][(nh) * 2 + ni], 0, 0, 0); \
    } \
} while (0)
#define SBAR() do { \
    __builtin_amdgcn_s_barrier(); \
    __builtin_amdgcn_sched_barrier(0); \
} while (0)
// P = A0-frag buffer for this tile, Q = A1-frag buffer (and next-tile A0 prefetch dest)
#define KTILE(buf, kt, P, Q, SP0, SPB0, SPP3, RDN, VM2) do { \
    /* P0: uses (P,b0); prefetch A1(kt)->Q; stage Ah1(kt+1) */ \
    SBAR(); \
    LD_An(buf, 1, Q); \
    if (SP0) STG_A((buf) ^ 1, 1, (kt) + 1); \
    __builtin_amdgcn_s_setprio(1); MMn(P, 0, 0, b0); __builtin_amdgcn_s_setprio(0); \
    /* P1: uses (Q,b0); prefetch B1(kt) */ \
    SBAR(); \
    LD_Bn(buf, 1, b1); \
    __builtin_amdgcn_s_setprio(1); MMn(Q, 1, 0, b0); __builtin_amdgcn_s_setprio(0); \
    /* P2: all-waves drain + barrier; uses (Q,b1); prefetch A0(kt+1)->Q (WAR after MM); stage B0(kt+2) */ \
    if (VM2) { asm volatile("s_waitcnt vmcnt(0)"); } \
    __builtin_amdgcn_sched_barrier(0); \
    SBAR(); \
    __builtin_amdgcn_s_setprio(1); MMn(Q, 1, 1, b1); __builtin_amdgcn_s_setprio(0); \
    if (RDN) LD_An((buf) ^ 1, 0, Q); \
    if (SPB0) STG_B(buf, 0, (kt) + 2); \
    /* P3: uses (P,b1); prefetch B0(kt+1); stage Ah0(kt+2), B1(kt+2) */ \
    SBAR(); \
    if (RDN) LD_Bn((buf) ^ 1, 0, b0); \
    if (SPP3) { STG_A(buf, 0, (kt) + 2); STG_B(buf, 1, (kt) + 2); } \
    __builtin_amdgcn_s_setprio(1); MMn(P, 0, 1, b1); __builtin_amdgcn_s_setprio(0); \
} while (0)

    f32x4 acc[8][4] = {};
    s16x8 X[4][2], Y[4][2], b0[2][2], b1[2][2];

    // prologue: stage tile0 fully; drain; read A0(0)->X, B0(0)->b0;
    // then issue tile1's {B0, Ah0, B1} = 6 in flight (steady-state queue shape).
    STG_A(0, 0, 0); STG_A(0, 1, 0); STG_B(0, 0, 0); STG_B(0, 1, 0);
    asm volatile("s_waitcnt vmcnt(0)");
    __builtin_amdgcn_sched_barrier(0);
    SBAR();
    LD_An(0, 0, X);
    LD_Bn(0, 0, b0);
    STG_B(1, 0, 1);
    STG_A(1, 0, 1); STG_B(1, 1, 1);

#pragma clang loop unroll(disable)
    for (int it = 0; it < 7; ++it) {    // tiles 0..13: full staging
        int kt = it * 2;
        KTILE(0, kt,     X, Y, 1, 1, 1, 1, 1);
        KTILE(1, kt + 1, Y, X, 1, 1, 1, 1, 1);
    }
    KTILE(0, 14, X, Y, 1, 0, 0, 1, 1);  // stages only Ah1(15)
    KTILE(1, 15, Y, X, 0, 0, 0, 0, 0);  // drain tile

#undef KTILE
#undef SBAR
#undef MMn
#undef LD_Bn
#undef LD_An
#undef STG_B
#undef STG_A

    // Epilogue. C/D layout: col = lane&15, row = quad*4 + reg  [verified m89/m91]
#pragma unroll
    for (int ni = 0; ni < 4; ++ni) {
        int gn = n0 + wn * 64 + ni * 16 + l16;
        float bi = bias[t * NSIZE + gn];
#pragma unroll
        for (int mi = 0; mi < 8; ++mi) {
#pragma unroll
            for (int r = 0; r < 4; ++r) {
                int gm = m0 + wm * 128 + mi * 16 + quad * 4 + r;
                size_t o = (size_t)(gm * T_SZ + t) * NSIZE + gn;
                float v = acc[mi][ni][r] + bi;
                if (EPI == 0) {
                    out_bf[o] = f2bf(v);
                } else {
                    out_f[o] = v + resid[o];
                }
            }
        }
    }
}

// ---------------- cross-task attention: 16 lanes per (b,h), 8 dims/lane ----------------
__global__ __launch_bounds__(256) void attn_kernel(const unsigned short* __restrict__ qkv,
                                                   unsigned short* __restrict__ ctx) {
    const int tid = threadIdx.x;
    const int li  = tid & 15;
    const int g   = blockIdx.x * 16 + (tid >> 4);   // [0, B*H)
    const int b   = g >> 3, h = g & 7;
    const int d0  = li * 8;

    const unsigned short* base = qkv + (size_t)b * (T_SZ * NQKV) + h * DH_SZ + d0;
    float qf[4][8], kf[4][8], vf[4][8];
#pragma unroll
    for (int i = 0; i < 4; i++) {
        const unsigned short* p = base + (size_t)i * NQKV;
        s16x8 qv = *reinterpret_cast<const s16x8*>(p);
        s16x8 kv = *reinterpret_cast<const s16x8*>(p + C_SZ);
        s16x8 vv = *reinterpret_cast<const s16x8*>(p + 2 * C_SZ);
#pragma unroll
        for (int e = 0; e < 8; e++) {
            qf[i][e] = bf2f((unsigned short)qv[e]);
            kf[i][e] = bf2f((unsigned short)kv[e]);
            vf[i][e] = bf2f((unsigned short)vv[e]);
        }
    }
    float s[4][4];
#pragma unroll
    for (int i = 0; i < 4; i++)
#pragma unroll
        for (int j = 0; j < 4; j++) {
            float p = 0.0f;
#pragma unroll
            for (int e = 0; e < 8; e++) p += qf[i][e] * kf[j][e];
            p += __shfl_xor(p, 8);
            p += __shfl_xor(p, 4);
            p += __shfl_xor(p, 2);
            p += __shfl_xor(p, 1);
            s[i][j] = p * SCALE_F;
        }
#pragma unroll
    for (int i = 0; i < 4; i++) {
        float m = fmaxf(fmaxf(s[i][0], s[i][1]), fmaxf(s[i][2], s[i][3]));
        float e0 = __expf(s[i][0] - m), e1 = __expf(s[i][1] - m);
        float e2 = __expf(s[i][2] - m), e3 = __expf(s[i][3] - m);
        float inv = 1.0f / (e0 + e1 + e2 + e3);
        s[i][0] = e0 * inv; s[i][1] = e1 * inv; s[i][2] = e2 * inv; s[i][3] = e3 * inv;
    }
#pragma unroll
    for (int i = 0; i < 4; i++) {
        s16x8 ov;
#pragma unroll
        for (int e = 0; e < 8; e++) {
            float o = s[i][0] * vf[0][e] + s[i][1] * vf[1][e]
                    + s[i][2] * vf[2][e] + s[i][3] * vf[3][e];
            ov[e] = (short)f2bf(o);
        }
        *reinterpret_cast<s16x8*>(ctx + (size_t)(b * T_SZ + i) * C_SZ + h * DH_SZ + d0) = ov;
    }
}

// ---------------- LayerNorm over C, one block per (b,t) row ----------------
__global__ __launch_bounds__(256) void ln_kernel(const float* __restrict__ y,
                                                 const float* __restrict__ gamma,
                                                 const float* __restrict__ beta,
                                                 float* __restrict__ out) {
    int row = blockIdx.x;
    int lane = threadIdx.x & 63, wave = threadIdx.x >> 6;
    float4 v = reinterpret_cast<const float4*>(y + (size_t)row * C_SZ)[threadIdx.x];
    float s  = v.x + v.y + v.z + v.w;
    float ss = v.x * v.x + v.y * v.y + v.z * v.z + v.w * v.w;
#pragma unroll
    for (int off = 32; off > 0; off >>= 1) { s += __shfl_xor(s, off); ss += __shfl_xor(ss, off); }
    __shared__ float red[8];
    if (lane == 0) { red[wave] = s; red[wave + 4] = ss; }
    __syncthreads();
    float S  = red[0] + red[1] + red[2] + red[3];
    float SS = red[4] + red[5] + red[6] + red[7];
    float mean = S * (1.0f / C_SZ);
    float var  = SS * (1.0f / C_SZ) - mean * mean;
    float inv  = rsqrtf(var + 1e-5f);
    float4 g  = reinterpret_cast<const float4*>(gamma)[threadIdx.x];
    float4 be = reinterpret_cast<const float4*>(beta)[threadIdx.x];
    float4 o;
    o.x = (v.x - mean) * inv * g.x + be.x;
    o.y = (v.y - mean) * inv * g.y + be.y;
    o.z = (v.z - mean) * inv * g.z + be.z;
    o.w = (v.w - mean) * inv * g.w + be.w;
    reinterpret_cast<float4*>(out + (size_t)row * C_SZ)[threadIdx.x] = o;
}

extern "C" void kernel_launch(void* const* d_in, const int* in_sizes, int n_in,
                              void* d_out, int out_size, void* d_ws, size_t ws_size,
                              hipStream_t stream) {
    const float* feats = (const float*)d_in[0];   // [B,T,C]
    const float* Wqkv  = (const float*)d_in[1];   // [T,C,3C]
    const float* bqkv  = (const float*)d_in[2];   // [T,3C]
    const float* Wproj = (const float*)d_in[3];   // [T,C,C]
    const float* bproj = (const float*)d_in[4];   // [T,C]
    const float* gamma = (const float*)d_in[5];   // [C]
    const float* beta  = (const float*)d_in[6];   // [C]
    float* out = (float*)d_out;

    // ws layout (bytes):
    //   [0,   33.5M)  feats_bf16  [B,T,C]
    //   [33.5M, 58.7M) WqkvT bf16 [T,3C,C]
    //   [58.7M, 67.1M) WprojT bf16 [T,C,C]
    //   [67.1M, 167.8M) qkv bf16 [B,T,3C]   (later aliased by y fp32 [B,T,C])
    //   [167.8M, 201.3M) ctx bf16 [B,T,C]
    char* ws = (char*)d_ws;
    unsigned short* feats_bf = (unsigned short*)(ws);
    unsigned short* wqkv_t   = (unsigned short*)(ws + 33554432);
    unsigned short* wproj_t  = (unsigned short*)(ws + 58720256);
    unsigned short* qkv      = (unsigned short*)(ws + 67108864);
    unsigned short* ctx      = (unsigned short*)(ws + 167772160);
    float* ybuf              = (float*)(ws + 67108864);   // aliases qkv (dead after attn)

    cvt_f32_bf16<<<16384, 256, 0, stream>>>(feats, feats_bf, (B_SZ * T_SZ * C_SZ) / 4);
    transpose_cvt<<<dim3(96, 32, 4), dim3(32, 8), 0, stream>>>(Wqkv, wqkv_t, C_SZ, NQKV);
    transpose_cvt<<<dim3(32, 32, 4), dim3(32, 8), 0, stream>>>(Wproj, wproj_t, C_SZ, C_SZ);

    // QKV: grid = (3072/256)*(4096/256)*4 = 768 blocks of 512
    gemm256<NQKV, 0><<<dim3(768), 512, 0, stream>>>(
        feats_bf, wqkv_t, bqkv, nullptr, qkv, nullptr);

    attn_kernel<<<(B_SZ * H_SZ) / 16, 256, 0, stream>>>(qkv, ctx);

    // proj: grid = (1024/256)*(4096/256)*4 = 256 blocks of 512
    gemm256<C_SZ, 1><<<dim3(256), 512, 0, stream>>>(
        ctx, wproj_t, bproj, feats, nullptr, ybuf);

    ln_kernel<<<B_SZ * T_SZ, 256, 0, stream>>>(ybuf, gamma, beta, out);
}

// Round 5
// 405.400 us; speedup vs baseline: 1.0913x; 1.0913x over previous
//
#include <hip/hip_runtime.h>
#include <hip/hip_bf16.h>
#include <cstdint>
#include <cstddef>

// Problem constants
#define B_SZ 4096
#define T_SZ 4
#define C_SZ 1024
#define H_SZ 8
#define DH_SZ 128
#define NQKV 3072                      // 3*C
#define SCALE_F 0.08838834764831845f   // 128^-0.5

typedef float f32x4 __attribute__((ext_vector_type(4)));
typedef short s16x8 __attribute__((ext_vector_type(8)));

static __device__ __forceinline__ float bf2f(unsigned short u) {
    union { unsigned int i; float f; } x; x.i = ((unsigned int)u) << 16; return x.f;
}
static __device__ __forceinline__ unsigned short f2bf(float f) {
    union { unsigned int i; float f; } x; x.f = f;
    unsigned int r = x.i + 0x7FFFu + ((x.i >> 16) & 1u);   // RNE
    return (unsigned short)(r >> 16);
}

// async global->LDS, 16B per lane; lds base must be wave-uniform (HW adds lane*16)
typedef const __attribute__((address_space(1))) void* gas_ptr;
typedef __attribute__((address_space(3))) void* las_ptr;
static __device__ __forceinline__ void async16(const void* g, void* l) {
    __builtin_amdgcn_global_load_lds((gas_ptr)g, (las_ptr)l, 16, 0, 0);
}

// ---------------- elementwise fp32 -> bf16 ----------------
__global__ __launch_bounds__(256) void cvt_f32_bf16(const float* __restrict__ src,
                                                    unsigned short* __restrict__ dst, int n4) {
    int i = blockIdx.x * 256 + threadIdx.x;
    if (i >= n4) return;
    float4 v = reinterpret_cast<const float4*>(src)[i];
    ushort4 o;
    o.x = f2bf(v.x); o.y = f2bf(v.y); o.z = f2bf(v.z); o.w = f2bf(v.w);
    reinterpret_cast<ushort4*>(dst)[i] = o;
}

// ---------------- transpose + convert: src[K][N] fp32 -> dst[N][K] bf16 (per z=task) --------
__global__ __launch_bounds__(256) void transpose_cvt(const float* __restrict__ src,
                                                     unsigned short* __restrict__ dst,
                                                     int K, int N) {
    __shared__ float tile[32][33];
    const float* s = src + (size_t)blockIdx.z * K * N;
    unsigned short* d = dst + (size_t)blockIdx.z * K * N;
    int n0 = blockIdx.x * 32, k0 = blockIdx.y * 32;
    int tx = threadIdx.x, ty = threadIdx.y;
#pragma unroll
    for (int i = 0; i < 4; i++) {
        int k = k0 + ty + i * 8;
        tile[ty + i * 8][tx] = s[(size_t)k * N + n0 + tx];
    }
    __syncthreads();
#pragma unroll
    for (int i = 0; i < 4; i++) {
        int n = n0 + ty + i * 8;
        d[(size_t)n * K + k0 + tx] = f2bf(tile[tx][ty + i * 8]);
    }
}

// ---------------- 256x256 bf16 MFMA GEMM, 2-region/tile compiler-scheduled ----------------
// A: bf16, row m of task t at A + t*C + m*(T*C), K = C = 1024
// Bt: bf16 [T][NSIZE][K] (B transposed), bias: fp32 [T][NSIZE]
//
// ROUND-5: round-3 buffers/staging/vmcnt(6), but NO lgkmcnt(0) drains (plain
// compiler-tracked ds_reads -> counted lgkm waits, reads interleave with MFMA),
// and only TWO walls (s_barrier + sched_barrier(0)) per tile:
//   region A: vmcnt(6); WALL; read bq0,A0,bq1 (16 reads); stage A1(kt+1)->buf^1;
//             MM(0,0) MM(0,1)   (32 MFMA)
//   region B: WALL; read A1 (8 reads, overwrites af); stage B0,A0,B1(kt+2)->buf;
//             MM(1,1) MM(1,0)   (32 MFMA)
// Register budget: acc 128 AGPR + frags af/bq0/bq1 = 64 arch VGPR (round-4's 96
// spilled; arch cap is 128 since 256/wave total at 2 waves/SIMD).
// Overwrite ledger (>=1 barrier between readers' retirement and staging issue;
// reads retire before their consuming MFMA issues, which is before the next wall):
//   A region A stage A1(kt+1)->buf^1: last reads of buf^1.A1 were (kt-1) region B,
//     retired before (kt-1).B MFMAs -> before kt.A wall.                       OK
//   B region stages into buf: B0 read@A (MM(0,0)), A0 read@A, B1 read@A (MM(0,1));
//     all retired before kt.B wall; stage issued after it.                     OK
// vmcnt(6) FIFO: entry queue (oldest->newest) = B0(kt),A0(kt),B1(kt) [staged
// (kt-1).B], A1(kt) [(kt-0?).. staged (kt-1).A]: wait to <=6 retires through
// A1(kt) -> tile kt fully resident. Last tile uses vmcnt(0).
template<int NSIZE, int EPI>
__global__ __launch_bounds__(512, 1) void gemm256(
    const unsigned short* __restrict__ A,
    const unsigned short* __restrict__ Bt,
    const float* __restrict__ bias,
    const float* __restrict__ resid,
    unsigned short* __restrict__ out_bf,
    float* __restrict__ out_f)
{
    constexpr int BK  = 64;
    constexpr int NBX = NSIZE / 256;   // 12 (qkv) or 4 (proj)
    constexpr int NBY = B_SZ / 256;    // 16
    constexpr int NWG = NBX * NBY * T_SZ;   // 768 / 256, both % 8 == 0

    __shared__ __align__(16) unsigned short lds[65536];   // 128 KiB
    // A buf0 [0,16384) buf1 [16384,32768); B buf0 [32768,49152) buf1 [49152,65536)
    // within buf: half0 [0,8192), half1 [8192,16384); row stride 64 ushorts

    // XCD-aware swizzle (T1)
    const int bid = blockIdx.x;
    const int swz = (bid & 7) * (NWG >> 3) + (bid >> 3);
    const int by  = swz & (NBY - 1);
    const int tmp = swz >> 4;
    const int bx  = tmp % NBX;
    const int t   = tmp / NBX;
    const int m0  = by * 256;
    const int n0  = bx * 256;

    const int tid  = threadIdx.x;
    const int lane = tid & 63;
    const int w    = tid >> 6;
    const int wm   = w >> 2;        // 0..1: which 128-row A half
    const int wn   = w & 3;         // 0..3: which 64-col B slice
    const int quad = lane >> 4;
    const int l16  = lane & 15;

    // ---- staging slot precompute (2 insts/thread per half-tile) ----
    // slot q = (w*2+i)*64 + lane; row = q>>3; stored chunk = q&7;
    // fetched data chunk = (q&7) ^ (row&7)  (inverse-swizzled global source)
    const int q0  = w * 128 + lane;
    const int q1  = q0 + 64;
    const int r0  = q0 >> 3, ch0 = (q0 & 7) ^ (r0 & 7);
    const int r1  = q1 >> 3, ch1 = (q1 & 7) ^ (r1 & 7);
    const unsigned short* Abase = A + (size_t)t * C_SZ;
    const unsigned short* Bbase = Bt + (size_t)t * NSIZE * C_SZ;
    const unsigned short* gA0 = Abase + (size_t)(m0 + r0) * (T_SZ * C_SZ) + ch0 * 8;
    const unsigned short* gA1 = Abase + (size_t)(m0 + r1) * (T_SZ * C_SZ) + ch1 * 8;
    const unsigned short* gB0 = Bbase + (size_t)(n0 + r0) * C_SZ + ch0 * 8;
    const unsigned short* gB1 = Bbase + (size_t)(n0 + r1) * C_SZ + ch1 * 8;
    unsigned short* dA0 = &lds[(w * 2 + 0) * 512];          // wave-uniform bases
    unsigned short* dA1 = &lds[(w * 2 + 1) * 512];
    unsigned short* dB0 = &lds[32768 + (w * 2 + 0) * 512];
    unsigned short* dB1 = &lds[32768 + (w * 2 + 1) * 512];

#define STG_A(buf, h, kt) do { \
    async16(gA0 + (size_t)(h) * 128 * (T_SZ * C_SZ) + (kt) * BK, dA0 + (buf) * 16384 + (h) * 8192); \
    async16(gA1 + (size_t)(h) * 128 * (T_SZ * C_SZ) + (kt) * BK, dA1 + (buf) * 16384 + (h) * 8192); \
} while (0)
#define STG_B(buf, h, kt) do { \
    async16(gB0 + (size_t)(h) * 128 * C_SZ + (kt) * BK, dB0 + (buf) * 16384 + (h) * 8192); \
    async16(gB1 + (size_t)(h) * 128 * C_SZ + (kt) * BK, dB1 + (buf) * 16384 + (h) * 8192); \
} while (0)

    // ---- fragment read bases; chunk swizzle: stored = (ks*4+quad) ^ (l16&7) ----
    const int s7   = l16 & 7;
    const int swk0 = ((0 * 4 + quad) ^ s7) * 8;
    const int swk1 = ((1 * 4 + quad) ^ s7) * 8;
    const unsigned short* aR = &lds[wm * 8192 + l16 * 64];
    const unsigned short* bR = &lds[32768 + (wn >> 1) * 8192 + ((wn & 1) * 64 + l16) * 64];

#define LD_A(buf, mh) do { \
    _Pragma("unroll") \
    for (int mi = 0; mi < 4; ++mi) { \
        af[mi][0] = *(const s16x8*)(aR + (buf) * 16384 + ((mh) * 4 + mi) * 1024 + swk0); \
        af[mi][1] = *(const s16x8*)(aR + (buf) * 16384 + ((mh) * 4 + mi) * 1024 + swk1); \
    } \
} while (0)
#define LD_B(buf, nh, dst) do { \
    _Pragma("unroll") \
    for (int ni = 0; ni < 2; ++ni) { \
        dst[ni][0] = *(const s16x8*)(bR + (buf) * 16384 + ((nh) * 2 + ni) * 1024 + swk0); \
        dst[ni][1] = *(const s16x8*)(bR + (buf) * 16384 + ((nh) * 2 + ni) * 1024 + swk1); \
    } \
} while (0)
#define MM(mh, nh, bsrc) do { \
    _Pragma("unroll") \
    for (int mi = 0; mi < 4; ++mi) \
    _Pragma("unroll") \
    for (int ni = 0; ni < 2; ++ni) { \
        acc[(mh) * 4 + mi][(nh) * 2 + ni] = __builtin_amdgcn_mfma_f32_16x16x32_bf16( \
            af[mi][0], bsrc[ni][0], acc[(mh) * 4 + mi][(nh) * 2 + ni], 0, 0, 0); \
        acc[(mh) * 4 + mi][(nh) * 2 + ni] = __builtin_amdgcn_mfma_f32_16x16x32_bf16( \
            af[mi][1], bsrc[ni][1], acc[(mh) * 4 + mi][(nh) * 2 + ni], 0, 0, 0); \
    } \
} while (0)
// WALL: barrier + hard scheduling wall (no motion across). NO lgkm/vm drain here:
// within a region the compiler interleaves ds_reads with MFMA via counted lgkmcnt.
#define WALL() do { \
    __builtin_amdgcn_s_barrier(); \
    __builtin_amdgcn_sched_barrier(0); \
} while (0)
#define KTILE(buf, kt, SP0, SP23, VMC) do { \
    /* region A */ \
    asm volatile("s_waitcnt vmcnt(" #VMC ")"); \
    __builtin_amdgcn_sched_barrier(0); \
    WALL(); \
    LD_B(buf, 0, bq0); \
    LD_A(buf, 0); \
    LD_B(buf, 1, bq1); \
    if (SP0) STG_A((buf) ^ 1, 1, (kt) + 1); \
    __builtin_amdgcn_s_setprio(1); MM(0, 0, bq0); MM(0, 1, bq1); __builtin_amdgcn_s_setprio(0); \
    /* region B */ \
    WALL(); \
    LD_A(buf, 1); \
    if (SP23) { STG_B(buf, 0, (kt) + 2); STG_A(buf, 0, (kt) + 2); STG_B(buf, 1, (kt) + 2); } \
    __builtin_amdgcn_s_setprio(1); MM(1, 1, bq1); MM(1, 0, bq0); __builtin_amdgcn_s_setprio(0); \
} while (0)

    f32x4 acc[8][4] = {};
    s16x8 af[4][2], bq0[2][2], bq1[2][2];

    // prologue: queue mirrors steady state (oldest->newest):
    //   tile0 {A0,B0,B1} , tile0 A1 , tile1 {B0,A0,B1}  = 14 loads in flight.
    // First KTILE's vmcnt(6) retires through A1(0) -> tile0 fully resident.
    STG_A(0, 0, 0); STG_B(0, 0, 0); STG_B(0, 1, 0);
    STG_A(0, 1, 0);
    STG_B(1, 0, 1); STG_A(1, 0, 1); STG_B(1, 1, 1);

#pragma clang loop unroll(disable)
    for (int it = 0; it < 7; ++it) {    // tiles 0..13: full staging
        int kt = it * 2;
        KTILE(0, kt,     1, 1, 6);
        KTILE(1, kt + 1, 1, 1, 6);
    }
    KTILE(0, 14, 1, 0, 6);              // stages only A1(15)
    KTILE(1, 15, 0, 0, 0);              // drain tile

#undef KTILE
#undef WALL
#undef MM
#undef LD_B
#undef LD_A
#undef STG_B
#undef STG_A

    // Epilogue. C/D layout: col = lane&15, row = quad*4 + reg  [verified m89/m91]
#pragma unroll
    for (int ni = 0; ni < 4; ++ni) {
        int gn = n0 + wn * 64 + ni * 16 + l16;
        float bi = bias[t * NSIZE + gn];
#pragma unroll
        for (int mi = 0; mi < 8; ++mi) {
#pragma unroll
            for (int r = 0; r < 4; ++r) {
                int gm = m0 + wm * 128 + mi * 16 + quad * 4 + r;
                size_t o = (size_t)(gm * T_SZ + t) * NSIZE + gn;
                float v = acc[mi][ni][r] + bi;
                if (EPI == 0) {
                    out_bf[o] = f2bf(v);
                } else {
                    out_f[o] = v + resid[o];
                }
            }
        }
    }
}

// ---------------- cross-task attention: 16 lanes per (b,h), 8 dims/lane ----------------
__global__ __launch_bounds__(256) void attn_kernel(const unsigned short* __restrict__ qkv,
                                                   unsigned short* __restrict__ ctx) {
    const int tid = threadIdx.x;
    const int li  = tid & 15;
    const int g   = blockIdx.x * 16 + (tid >> 4);   // [0, B*H)
    const int b   = g >> 3, h = g & 7;
    const int d0  = li * 8;

    const unsigned short* base = qkv + (size_t)b * (T_SZ * NQKV) + h * DH_SZ + d0;
    float qf[4][8], kf[4][8], vf[4][8];
#pragma unroll
    for (int i = 0; i < 4; i++) {
        const unsigned short* p = base + (size_t)i * NQKV;
        s16x8 qv = *reinterpret_cast<const s16x8*>(p);
        s16x8 kv = *reinterpret_cast<const s16x8*>(p + C_SZ);
        s16x8 vv = *reinterpret_cast<const s16x8*>(p + 2 * C_SZ);
#pragma unroll
        for (int e = 0; e < 8; e++) {
            qf[i][e] = bf2f((unsigned short)qv[e]);
            kf[i][e] = bf2f((unsigned short)kv[e]);
            vf[i][e] = bf2f((unsigned short)vv[e]);
        }
    }
    float s[4][4];
#pragma unroll
    for (int i = 0; i < 4; i++)
#pragma unroll
        for (int j = 0; j < 4; j++) {
            float p = 0.0f;
#pragma unroll
            for (int e = 0; e < 8; e++) p += qf[i][e] * kf[j][e];
            p += __shfl_xor(p, 8);
            p += __shfl_xor(p, 4);
            p += __shfl_xor(p, 2);
            p += __shfl_xor(p, 1);
            s[i][j] = p * SCALE_F;
        }
#pragma unroll
    for (int i = 0; i < 4; i++) {
        float m = fmaxf(fmaxf(s[i][0], s[i][1]), fmaxf(s[i][2], s[i][3]));
        float e0 = __expf(s[i][0] - m), e1 = __expf(s[i][1] - m);
        float e2 = __expf(s[i][2] - m), e3 = __expf(s[i][3] - m);
        float inv = 1.0f / (e0 + e1 + e2 + e3);
        s[i][0] = e0 * inv; s[i][1] = e1 * inv; s[i][2] = e2 * inv; s[i][3] = e3 * inv;
    }
#pragma unroll
    for (int i = 0; i < 4; i++) {
        s16x8 ov;
#pragma unroll
        for (int e = 0; e < 8; e++) {
            float o = s[i][0] * vf[0][e] + s[i][1] * vf[1][e]
                    + s[i][2] * vf[2][e] + s[i][3] * vf[3][e];
            ov[e] = (short)f2bf(o);
        }
        *reinterpret_cast<s16x8*>(ctx + (size_t)(b * T_SZ + i) * C_SZ + h * DH_SZ + d0) = ov;
    }
}

// ---------------- LayerNorm over C, one block per (b,t) row ----------------
__global__ __launch_bounds__(256) void ln_kernel(const float* __restrict__ y,
                                                 const float* __restrict__ gamma,
                                                 const float* __restrict__ beta,
                                                 float* __restrict__ out) {
    int row = blockIdx.x;
    int lane = threadIdx.x & 63, wave = threadIdx.x >> 6;
    float4 v = reinterpret_cast<const float4*>(y + (size_t)row * C_SZ)[threadIdx.x];
    float s  = v.x + v.y + v.z + v.w;
    float ss = v.x * v.x + v.y * v.y + v.z * v.z + v.w * v.w;
#pragma unroll
    for (int off = 32; off > 0; off >>= 1) { s += __shfl_xor(s, off); ss += __shfl_xor(ss, off); }
    __shared__ float red[8];
    if (lane == 0) { red[wave] = s; red[wave + 4] = ss; }
    __syncthreads();
    float S  = red[0] + red[1] + red[2] + red[3];
    float SS = red[4] + red[5] + red[6] + red[7];
    float mean = S * (1.0f / C_SZ);
    float var  = SS * (1.0f / C_SZ) - mean * mean;
    float inv  = rsqrtf(var + 1e-5f);
    float4 g  = reinterpret_cast<const float4*>(gamma)[threadIdx.x];
    float4 be = reinterpret_cast<const float4*>(beta)[threadIdx.x];
    float4 o;
    o.x = (v.x - mean) * inv * g.x + be.x;
    o.y = (v.y - mean) * inv * g.y + be.y;
    o.z = (v.z - mean) * inv * g.z + be.z;
    o.w = (v.w - mean) * inv * g.w + be.w;
    reinterpret_cast<float4*>(out + (size_t)row * C_SZ)[threadIdx.x] = o;
}

extern "C" void kernel_launch(void* const* d_in, const int* in_sizes, int n_in,
                              void* d_out, int out_size, void* d_ws, size_t ws_size,
                              hipStream_t stream) {
    const float* feats = (const float*)d_in[0];   // [B,T,C]
    const float* Wqkv  = (const float*)d_in[1];   // [T,C,3C]
    const float* bqkv  = (const float*)d_in[2];   // [T,3C]
    const float* Wproj = (const float*)d_in[3];   // [T,C,C]
    const float* bproj = (const float*)d_in[4];   // [T,C]
    const float* gamma = (const float*)d_in[5];   // [C]
    const float* beta  = (const float*)d_in[6];   // [C]
    float* out = (float*)d_out;

    // ws layout (bytes):
    //   [0,   33.5M)  feats_bf16  [B,T,C]
    //   [33.5M, 58.7M) WqkvT bf16 [T,3C,C]
    //   [58.7M, 67.1M) WprojT bf16 [T,C,C]
    //   [67.1M, 167.8M) qkv bf16 [B,T,3C]   (later aliased by y fp32 [B,T,C])
    //   [167.8M, 201.3M) ctx bf16 [B,T,C]
    char* ws = (char*)d_ws;
    unsigned short* feats_bf = (unsigned short*)(ws);
    unsigned short* wqkv_t   = (unsigned short*)(ws + 33554432);
    unsigned short* wproj_t  = (unsigned short*)(ws + 58720256);
    unsigned short* qkv      = (unsigned short*)(ws + 67108864);
    unsigned short* ctx      = (unsigned short*)(ws + 167772160);
    float* ybuf              = (float*)(ws + 67108864);   // aliases qkv (dead after attn)

    cvt_f32_bf16<<<16384, 256, 0, stream>>>(feats, feats_bf, (B_SZ * T_SZ * C_SZ) / 4);
    transpose_cvt<<<dim3(96, 32, 4), dim3(32, 8), 0, stream>>>(Wqkv, wqkv_t, C_SZ, NQKV);
    transpose_cvt<<<dim3(32, 32, 4), dim3(32, 8), 0, stream>>>(Wproj, wproj_t, C_SZ, C_SZ);

    // QKV: grid = (3072/256)*(4096/256)*4 = 768 blocks of 512
    gemm256<NQKV, 0><<<dim3(768), 512, 0, stream>>>(
        feats_bf, wqkv_t, bqkv, nullptr, qkv, nullptr);

    attn_kernel<<<(B_SZ * H_SZ) / 16, 256, 0, stream>>>(qkv, ctx);

    // proj: grid = (1024/256)*(4096/256)*4 = 256 blocks of 512
    gemm256<C_SZ, 1><<<dim3(256), 512, 0, stream>>>(
        ctx, wproj_t, bproj, feats, nullptr, ybuf);

    ln_kernel<<<B_SZ * T_SZ, 256, 0, stream>>>(ybuf, gamma, beta, out);
}

// Round 6
// 387.014 us; speedup vs baseline: 1.1432x; 1.0475x over previous
//
#include <hip/hip_runtime.h>
#include <hip/hip_bf16.h>
#include <cstdint>
#include <cstddef>

// Problem constants
#define B_SZ 4096
#define T_SZ 4
#define C_SZ 1024
#define H_SZ 8
#define DH_SZ 128
#define NQKV 3072                      // 3*C
#define SCALE_F 0.08838834764831845f   // 128^-0.5

typedef float f32x4 __attribute__((ext_vector_type(4)));
typedef short s16x8 __attribute__((ext_vector_type(8)));

static __device__ __forceinline__ float bf2f(unsigned short u) {
    union { unsigned int i; float f; } x; x.i = ((unsigned int)u) << 16; return x.f;
}
static __device__ __forceinline__ unsigned short f2bf(float f) {
    union { unsigned int i; float f; } x; x.f = f;
    unsigned int r = x.i + 0x7FFFu + ((x.i >> 16) & 1u);   // RNE
    return (unsigned short)(r >> 16);
}

// async global->LDS, 16B per lane; lds base must be wave-uniform (HW adds lane*16)
typedef const __attribute__((address_space(1))) void* gas_ptr;
typedef __attribute__((address_space(3))) void* las_ptr;
static __device__ __forceinline__ void async16(const void* g, void* l) {
    __builtin_amdgcn_global_load_lds((gas_ptr)g, (las_ptr)l, 16, 0, 0);
}

// ---------------- elementwise fp32 -> bf16 (grid-stride, 2048 blocks) ----------------
__global__ __launch_bounds__(256) void cvt_f32_bf16(const float* __restrict__ src,
                                                    unsigned short* __restrict__ dst, int n4) {
    int stride = gridDim.x * 256;
    for (int i = blockIdx.x * 256 + threadIdx.x; i < n4; i += stride) {
        float4 v = reinterpret_cast<const float4*>(src)[i];
        ushort4 o;
        o.x = f2bf(v.x); o.y = f2bf(v.y); o.z = f2bf(v.z); o.w = f2bf(v.w);
        reinterpret_cast<ushort4*>(dst)[i] = o;
    }
}

// ---------------- transpose + convert: src[K][N] fp32 -> dst[N][K] bf16 (per z=task) --------
// 64(k) x 32(n) tile; ushort2 stores (128B per 32 lanes, was 64B with scalar stores).
// grid: (N/32, K/64, T), block (32,8).
__global__ __launch_bounds__(256) void transpose_cvt(const float* __restrict__ src,
                                                     unsigned short* __restrict__ dst,
                                                     int K, int N) {
    __shared__ float tile[64][33];
    const float* s = src + (size_t)blockIdx.z * K * N;
    unsigned short* d = dst + (size_t)blockIdx.z * K * N;
    int n0 = blockIdx.x * 32, k0 = blockIdx.y * 64;
    int tx = threadIdx.x, ty = threadIdx.y;
#pragma unroll
    for (int i = 0; i < 8; i++) {
        int k = k0 + ty + i * 8;
        tile[ty + i * 8][tx] = s[(size_t)k * N + n0 + tx];
    }
    __syncthreads();
#pragma unroll
    for (int i = 0; i < 4; i++) {
        int n = n0 + ty + i * 8;
        ushort2 o;
        o.x = f2bf(tile[2 * tx][ty + i * 8]);        // k = k0+2tx   (2-way LDS alias: free)
        o.y = f2bf(tile[2 * tx + 1][ty + i * 8]);    // k = k0+2tx+1
        *reinterpret_cast<ushort2*>(&d[(size_t)n * K + k0 + 2 * tx]) = o;
    }
}

// ---------------- 256x256 bf16 MFMA GEMM, 2-region/tile compiler-scheduled ----------------
// (structure frozen from round 5 — 789 TF, within 7% of m248's grouped-GEMM reference)
// A: bf16, row m of task t at A + t*C + m*(T*C), K = C = 1024
// Bt: bf16 [T][NSIZE][K], bias fp32 [T][NSIZE]; out_bf[(m*T+t)*NSIZE + n] = bf16(acc+bias)
template<int NSIZE>
__global__ __launch_bounds__(512, 1) void gemm256(
    const unsigned short* __restrict__ A,
    const unsigned short* __restrict__ Bt,
    const float* __restrict__ bias,
    unsigned short* __restrict__ out_bf)
{
    constexpr int BK  = 64;
    constexpr int NBX = NSIZE / 256;   // 12 (qkv) or 4 (proj)
    constexpr int NBY = B_SZ / 256;    // 16
    constexpr int NWG = NBX * NBY * T_SZ;   // 768 / 256, both % 8 == 0

    __shared__ __align__(16) unsigned short lds[65536];   // 128 KiB
    // A buf0 [0,16384) buf1 [16384,32768); B buf0 [32768,49152) buf1 [49152,65536)

    // XCD-aware swizzle (T1)
    const int bid = blockIdx.x;
    const int swz = (bid & 7) * (NWG >> 3) + (bid >> 3);
    const int by  = swz & (NBY - 1);
    const int tmp = swz >> 4;
    const int bx  = tmp % NBX;
    const int t   = tmp / NBX;
    const int m0  = by * 256;
    const int n0  = bx * 256;

    const int tid  = threadIdx.x;
    const int lane = tid & 63;
    const int w    = tid >> 6;
    const int wm   = w >> 2;        // 0..1: which 128-row A half
    const int wn   = w & 3;         // 0..3: which 64-col B slice
    const int quad = lane >> 4;
    const int l16  = lane & 15;

    // staging slot precompute: slot q -> row q>>3, stored chunk q&7,
    // fetched data chunk = (q&7)^(row&7)  (inverse-swizzled global source)
    const int q0  = w * 128 + lane;
    const int q1  = q0 + 64;
    const int r0  = q0 >> 3, ch0 = (q0 & 7) ^ (r0 & 7);
    const int r1  = q1 >> 3, ch1 = (q1 & 7) ^ (r1 & 7);
    const unsigned short* Abase = A + (size_t)t * C_SZ;
    const unsigned short* Bbase = Bt + (size_t)t * NSIZE * C_SZ;
    const unsigned short* gA0 = Abase + (size_t)(m0 + r0) * (T_SZ * C_SZ) + ch0 * 8;
    const unsigned short* gA1 = Abase + (size_t)(m0 + r1) * (T_SZ * C_SZ) + ch1 * 8;
    const unsigned short* gB0 = Bbase + (size_t)(n0 + r0) * C_SZ + ch0 * 8;
    const unsigned short* gB1 = Bbase + (size_t)(n0 + r1) * C_SZ + ch1 * 8;
    unsigned short* dA0 = &lds[(w * 2 + 0) * 512];          // wave-uniform bases
    unsigned short* dA1 = &lds[(w * 2 + 1) * 512];
    unsigned short* dB0 = &lds[32768 + (w * 2 + 0) * 512];
    unsigned short* dB1 = &lds[32768 + (w * 2 + 1) * 512];

#define STG_A(buf, h, kt) do { \
    async16(gA0 + (size_t)(h) * 128 * (T_SZ * C_SZ) + (kt) * BK, dA0 + (buf) * 16384 + (h) * 8192); \
    async16(gA1 + (size_t)(h) * 128 * (T_SZ * C_SZ) + (kt) * BK, dA1 + (buf) * 16384 + (h) * 8192); \
} while (0)
#define STG_B(buf, h, kt) do { \
    async16(gB0 + (size_t)(h) * 128 * C_SZ + (kt) * BK, dB0 + (buf) * 16384 + (h) * 8192); \
    async16(gB1 + (size_t)(h) * 128 * C_SZ + (kt) * BK, dB1 + (buf) * 16384 + (h) * 8192); \
} while (0)

    // fragment read bases; chunk swizzle: stored = (ks*4+quad) ^ (l16&7)
    const int s7   = l16 & 7;
    const int swk0 = ((0 * 4 + quad) ^ s7) * 8;
    const int swk1 = ((1 * 4 + quad) ^ s7) * 8;
    const unsigned short* aR = &lds[wm * 8192 + l16 * 64];
    const unsigned short* bR = &lds[32768 + (wn >> 1) * 8192 + ((wn & 1) * 64 + l16) * 64];

#define LD_A(buf, mh) do { \
    _Pragma("unroll") \
    for (int mi = 0; mi < 4; ++mi) { \
        af[mi][0] = *(const s16x8*)(aR + (buf) * 16384 + ((mh) * 4 + mi) * 1024 + swk0); \
        af[mi][1] = *(const s16x8*)(aR + (buf) * 16384 + ((mh) * 4 + mi) * 1024 + swk1); \
    } \
} while (0)
#define LD_B(buf, nh, dst) do { \
    _Pragma("unroll") \
    for (int ni = 0; ni < 2; ++ni) { \
        dst[ni][0] = *(const s16x8*)(bR + (buf) * 16384 + ((nh) * 2 + ni) * 1024 + swk0); \
        dst[ni][1] = *(const s16x8*)(bR + (buf) * 16384 + ((nh) * 2 + ni) * 1024 + swk1); \
    } \
} while (0)
#define MM(mh, nh, bsrc) do { \
    _Pragma("unroll") \
    for (int mi = 0; mi < 4; ++mi) \
    _Pragma("unroll") \
    for (int ni = 0; ni < 2; ++ni) { \
        acc[(mh) * 4 + mi][(nh) * 2 + ni] = __builtin_amdgcn_mfma_f32_16x16x32_bf16( \
            af[mi][0], bsrc[ni][0], acc[(mh) * 4 + mi][(nh) * 2 + ni], 0, 0, 0); \
        acc[(mh) * 4 + mi][(nh) * 2 + ni] = __builtin_amdgcn_mfma_f32_16x16x32_bf16( \
            af[mi][1], bsrc[ni][1], acc[(mh) * 4 + mi][(nh) * 2 + ni], 0, 0, 0); \
    } \
} while (0)
#define WALL() do { \
    __builtin_amdgcn_s_barrier(); \
    __builtin_amdgcn_sched_barrier(0); \
} while (0)
#define KTILE(buf, kt, SP0, SP23, VMC) do { \
    /* region A */ \
    asm volatile("s_waitcnt vmcnt(" #VMC ")"); \
    __builtin_amdgcn_sched_barrier(0); \
    WALL(); \
    LD_B(buf, 0, bq0); \
    LD_A(buf, 0); \
    LD_B(buf, 1, bq1); \
    if (SP0) STG_A((buf) ^ 1, 1, (kt) + 1); \
    __builtin_amdgcn_s_setprio(1); MM(0, 0, bq0); MM(0, 1, bq1); __builtin_amdgcn_s_setprio(0); \
    /* region B */ \
    WALL(); \
    LD_A(buf, 1); \
    if (SP23) { STG_B(buf, 0, (kt) + 2); STG_A(buf, 0, (kt) + 2); STG_B(buf, 1, (kt) + 2); } \
    __builtin_amdgcn_s_setprio(1); MM(1, 1, bq1); MM(1, 0, bq0); __builtin_amdgcn_s_setprio(0); \
} while (0)

    f32x4 acc[8][4] = {};
    s16x8 af[4][2], bq0[2][2], bq1[2][2];

    // prologue: queue (oldest->newest): tile0 {A0,B0,B1,A1}, tile1 {B0,A0,B1} = 14 in flight.
    // First KTILE's vmcnt(6) retires through A1(0) -> tile0 fully resident.
    STG_A(0, 0, 0); STG_B(0, 0, 0); STG_B(0, 1, 0);
    STG_A(0, 1, 0);
    STG_B(1, 0, 1); STG_A(1, 0, 1); STG_B(1, 1, 1);

#pragma clang loop unroll(disable)
    for (int it = 0; it < 7; ++it) {    // tiles 0..13: full staging
        int kt = it * 2;
        KTILE(0, kt,     1, 1, 6);
        KTILE(1, kt + 1, 1, 1, 6);
    }
    KTILE(0, 14, 1, 0, 6);              // stages only A1(15)
    KTILE(1, 15, 0, 0, 0);              // drain tile

#undef KTILE
#undef WALL
#undef MM
#undef LD_B
#undef LD_A
#undef STG_B
#undef STG_A

    // Epilogue. C/D layout: col = lane&15, row = quad*4 + reg  [verified m89/m91]
#pragma unroll
    for (int ni = 0; ni < 4; ++ni) {
        int gn = n0 + wn * 64 + ni * 16 + l16;
        float bi = bias[t * NSIZE + gn];
#pragma unroll
        for (int mi = 0; mi < 8; ++mi) {
#pragma unroll
            for (int r = 0; r < 4; ++r) {
                int gm = m0 + wm * 128 + mi * 16 + quad * 4 + r;
                size_t o = (size_t)(gm * T_SZ + t) * NSIZE + gn;
                out_bf[o] = f2bf(acc[mi][ni][r] + bi);
            }
        }
    }
}

// ---------------- cross-task attention: 16 lanes per (b,h), 8 dims/lane ----------------
__global__ __launch_bounds__(256) void attn_kernel(const unsigned short* __restrict__ qkv,
                                                   unsigned short* __restrict__ ctx) {
    const int tid = threadIdx.x;
    const int li  = tid & 15;
    const int g   = blockIdx.x * 16 + (tid >> 4);   // [0, B*H)
    const int b   = g >> 3, h = g & 7;
    const int d0  = li * 8;

    const unsigned short* base = qkv + (size_t)b * (T_SZ * NQKV) + h * DH_SZ + d0;
    float qf[4][8], kf[4][8], vf[4][8];
#pragma unroll
    for (int i = 0; i < 4; i++) {
        const unsigned short* p = base + (size_t)i * NQKV;
        s16x8 qv = *reinterpret_cast<const s16x8*>(p);
        s16x8 kv = *reinterpret_cast<const s16x8*>(p + C_SZ);
        s16x8 vv = *reinterpret_cast<const s16x8*>(p + 2 * C_SZ);
#pragma unroll
        for (int e = 0; e < 8; e++) {
            qf[i][e] = bf2f((unsigned short)qv[e]);
            kf[i][e] = bf2f((unsigned short)kv[e]);
            vf[i][e] = bf2f((unsigned short)vv[e]);
        }
    }
    float s[4][4];
#pragma unroll
    for (int i = 0; i < 4; i++)
#pragma unroll
        for (int j = 0; j < 4; j++) {
            float p = 0.0f;
#pragma unroll
            for (int e = 0; e < 8; e++) p += qf[i][e] * kf[j][e];
            p += __shfl_xor(p, 8);
            p += __shfl_xor(p, 4);
            p += __shfl_xor(p, 2);
            p += __shfl_xor(p, 1);
            s[i][j] = p * SCALE_F;
        }
#pragma unroll
    for (int i = 0; i < 4; i++) {
        float m = fmaxf(fmaxf(s[i][0], s[i][1]), fmaxf(s[i][2], s[i][3]));
        float e0 = __expf(s[i][0] - m), e1 = __expf(s[i][1] - m);
        float e2 = __expf(s[i][2] - m), e3 = __expf(s[i][3] - m);
        float inv = 1.0f / (e0 + e1 + e2 + e3);
        s[i][0] = e0 * inv; s[i][1] = e1 * inv; s[i][2] = e2 * inv; s[i][3] = e3 * inv;
    }
#pragma unroll
    for (int i = 0; i < 4; i++) {
        s16x8 ov;
#pragma unroll
        for (int e = 0; e < 8; e++) {
            float o = s[i][0] * vf[0][e] + s[i][1] * vf[1][e]
                    + s[i][2] * vf[2][e] + s[i][3] * vf[3][e];
            ov[e] = (short)f2bf(o);
        }
        *reinterpret_cast<s16x8*>(ctx + (size_t)(b * T_SZ + i) * C_SZ + h * DH_SZ + d0) = ov;
    }
}

// ---------------- fused residual + LayerNorm: wave per row, 4 rows/block ----------------
// x = bf2f(yb[row]) + feats[row]; out = (x-mu)*rsqrt(var+eps)*gamma + beta
// Lane owns cols {c*256 + lane*4 .. +4}, c=0..3 -> every load/store fully coalesced.
__global__ __launch_bounds__(256) void ln_fused(const unsigned short* __restrict__ yb,
                                                const float* __restrict__ feats,
                                                const float* __restrict__ gamma,
                                                const float* __restrict__ beta,
                                                float* __restrict__ out) {
    const int wave = threadIdx.x >> 6, lane = threadIdx.x & 63;
    const int row = blockIdx.x * 4 + wave;
    const unsigned short* yp = yb + (size_t)row * C_SZ;
    const float* fp = feats + (size_t)row * C_SZ;

    float x[4][4];
    float s = 0.0f, ss = 0.0f;
#pragma unroll
    for (int c = 0; c < 4; c++) {
        int col = c * 256 + lane * 4;
        ushort4 u = *reinterpret_cast<const ushort4*>(yp + col);
        float4 f = *reinterpret_cast<const float4*>(fp + col);
        x[c][0] = bf2f(u.x) + f.x;
        x[c][1] = bf2f(u.y) + f.y;
        x[c][2] = bf2f(u.z) + f.z;
        x[c][3] = bf2f(u.w) + f.w;
#pragma unroll
        for (int j = 0; j < 4; j++) { s += x[c][j]; ss += x[c][j] * x[c][j]; }
    }
#pragma unroll
    for (int off = 32; off > 0; off >>= 1) { s += __shfl_xor(s, off); ss += __shfl_xor(ss, off); }
    float mean = s * (1.0f / C_SZ);
    float var  = ss * (1.0f / C_SZ) - mean * mean;
    float inv  = rsqrtf(var + 1e-5f);
#pragma unroll
    for (int c = 0; c < 4; c++) {
        int col = c * 256 + lane * 4;
        float4 g  = *reinterpret_cast<const float4*>(gamma + col);
        float4 be = *reinterpret_cast<const float4*>(beta + col);
        float4 o;
        o.x = (x[c][0] - mean) * inv * g.x + be.x;
        o.y = (x[c][1] - mean) * inv * g.y + be.y;
        o.z = (x[c][2] - mean) * inv * g.z + be.z;
        o.w = (x[c][3] - mean) * inv * g.w + be.w;
        *reinterpret_cast<float4*>(out + (size_t)row * C_SZ + col) = o;
    }
}

extern "C" void kernel_launch(void* const* d_in, const int* in_sizes, int n_in,
                              void* d_out, int out_size, void* d_ws, size_t ws_size,
                              hipStream_t stream) {
    const float* feats = (const float*)d_in[0];   // [B,T,C]
    const float* Wqkv  = (const float*)d_in[1];   // [T,C,3C]
    const float* bqkv  = (const float*)d_in[2];   // [T,3C]
    const float* Wproj = (const float*)d_in[3];   // [T,C,C]
    const float* bproj = (const float*)d_in[4];   // [T,C]
    const float* gamma = (const float*)d_in[5];   // [C]
    const float* beta  = (const float*)d_in[6];   // [C]
    float* out = (float*)d_out;

    // ws layout (bytes):
    //   [0,   33.5M)  feats_bf16  [B,T,C]
    //   [33.5M, 58.7M) WqkvT bf16 [T,3C,C]
    //   [58.7M, 67.1M) WprojT bf16 [T,C,C]
    //   [67.1M, 167.8M) qkv bf16 [B,T,3C]   (later aliased by ybuf_bf [B,T,C] = 33.5MB)
    //   [167.8M, 201.3M) ctx bf16 [B,T,C]
    char* ws = (char*)d_ws;
    unsigned short* feats_bf = (unsigned short*)(ws);
    unsigned short* wqkv_t   = (unsigned short*)(ws + 33554432);
    unsigned short* wproj_t  = (unsigned short*)(ws + 58720256);
    unsigned short* qkv      = (unsigned short*)(ws + 67108864);
    unsigned short* ctx      = (unsigned short*)(ws + 167772160);
    unsigned short* ybuf_bf  = (unsigned short*)(ws + 67108864);  // aliases qkv (dead after attn)

    cvt_f32_bf16<<<2048, 256, 0, stream>>>(feats, feats_bf, (B_SZ * T_SZ * C_SZ) / 4);
    transpose_cvt<<<dim3(96, 16, 4), dim3(32, 8), 0, stream>>>(Wqkv, wqkv_t, C_SZ, NQKV);
    transpose_cvt<<<dim3(32, 16, 4), dim3(32, 8), 0, stream>>>(Wproj, wproj_t, C_SZ, C_SZ);

    // QKV: grid = (3072/256)*(4096/256)*4 = 768 blocks of 512
    gemm256<NQKV><<<dim3(768), 512, 0, stream>>>(feats_bf, wqkv_t, bqkv, qkv);

    attn_kernel<<<(B_SZ * H_SZ) / 16, 256, 0, stream>>>(qkv, ctx);

    // proj: grid = (1024/256)*(4096/256)*4 = 256 blocks of 512; pure bf16 epilogue
    gemm256<C_SZ><<<dim3(256), 512, 0, stream>>>(ctx, wproj_t, bproj, ybuf_bf);

    // fused residual + LN (wave per row)
    ln_fused<<<(B_SZ * T_SZ) / 4, 256, 0, stream>>>(ybuf_bf, feats, gamma, beta, out);
}

// Round 7
// 359.653 us; speedup vs baseline: 1.2301x; 1.0761x over previous
//
#include <hip/hip_runtime.h>
#include <hip/hip_bf16.h>
#include <cstdint>
#include <cstddef>

// Problem constants
#define B_SZ 4096
#define T_SZ 4
#define C_SZ 1024
#define H_SZ 8
#define DH_SZ 128
#define NQKV 3072                      // 3*C
#define SCALE_F 0.08838834764831845f   // 128^-0.5

typedef float f32x4 __attribute__((ext_vector_type(4)));
typedef short s16x8 __attribute__((ext_vector_type(8)));

static __device__ __forceinline__ float bf2f(unsigned short u) {
    union { unsigned int i; float f; } x; x.i = ((unsigned int)u) << 16; return x.f;
}
static __device__ __forceinline__ unsigned short f2bf(float f) {
    union { unsigned int i; float f; } x; x.f = f;
    unsigned int r = x.i + 0x7FFFu + ((x.i >> 16) & 1u);   // RNE
    return (unsigned short)(r >> 16);
}

// async global->LDS, 16B per lane; lds base must be wave-uniform (HW adds lane*16)
typedef const __attribute__((address_space(1))) void* gas_ptr;
typedef __attribute__((address_space(3))) void* las_ptr;
static __device__ __forceinline__ void async16(const void* g, void* l) {
    __builtin_amdgcn_global_load_lds((gas_ptr)g, (las_ptr)l, 16, 0, 0);
}

// ---------------- merged prep kernel ----------------
// blocks [0,6144):      transpose Wqkv  [C][3C] f32 -> wqkvT  [3C][C] bf16 (per task)
// blocks [6144,8192):   transpose Wproj [C][C]  f32 -> wprojT [C][C]  bf16 (per task)
// blocks [8192,12288):  permute+cvt feats [B][T][C] f32 -> featsT [T][B][C] bf16
__global__ __launch_bounds__(256) void prep_kernel(const float* __restrict__ Wqkv,
                                                   const float* __restrict__ Wproj,
                                                   const float* __restrict__ feats,
                                                   unsigned short* __restrict__ wqkvT,
                                                   unsigned short* __restrict__ wprojT,
                                                   unsigned short* __restrict__ featsT) {
    const int bid = blockIdx.x;
    const int tid = threadIdx.x;
    if (bid < 8192) {
        // transpose+cvt: 64(k) x 32(n) tile, ushort2 stores
        __shared__ float tile[64][33];
        const float* src; unsigned short* dst; int K = C_SZ, N; int bx, by, bz;
        if (bid < 6144) {
            N = NQKV; bx = bid % 96; by = (bid / 96) % 16; bz = bid / 1536;
            src = Wqkv;  dst = wqkvT;
        } else {
            int b2 = bid - 6144;
            N = C_SZ; bx = b2 % 32; by = (b2 / 32) % 16; bz = b2 / 512;
            src = Wproj; dst = wprojT;
        }
        const float* s = src + (size_t)bz * K * N;
        unsigned short* d = dst + (size_t)bz * K * N;
        int n0 = bx * 32, k0 = by * 64;
        int tx = tid & 31, ty = tid >> 5;
#pragma unroll
        for (int i = 0; i < 8; i++) {
            int k = k0 + ty + i * 8;
            tile[ty + i * 8][tx] = s[(size_t)k * N + n0 + tx];
        }
        __syncthreads();
#pragma unroll
        for (int i = 0; i < 4; i++) {
            int n = n0 + ty + i * 8;
            ushort2 o;
            o.x = f2bf(tile[2 * tx][ty + i * 8]);
            o.y = f2bf(tile[2 * tx + 1][ty + i * 8]);
            *reinterpret_cast<ushort2*>(&d[(size_t)n * K + k0 + 2 * tx]) = o;
        }
    } else {
        // feats permute+cvt: wave per (b,t) row
        const int wave = tid >> 6, lane = tid & 63;
        const int r = (bid - 8192) * 4 + wave;      // r = b*T + t
        const int b = r >> 2, t = r & 3;
        const float* fp = feats + (size_t)r * C_SZ;
        unsigned short* op = featsT + ((size_t)t * B_SZ + b) * C_SZ;
#pragma unroll
        for (int c = 0; c < 4; c++) {
            int col = c * 256 + lane * 4;
            float4 v = *reinterpret_cast<const float4*>(fp + col);
            ushort4 o;
            o.x = f2bf(v.x); o.y = f2bf(v.y); o.z = f2bf(v.z); o.w = f2bf(v.w);
            *reinterpret_cast<ushort4*>(op + col) = o;
        }
    }
}

// ---------------- 256x256 bf16 MFMA GEMM, 2-region/tile compiler-scheduled ----------------
// A: bf16 task-major [T][B][K] (dense per-task panel), K = C = 1024
// Bt: bf16 [T][NSIZE][K], bias fp32 [T][NSIZE]
// out_bf: task-major [T][B][NSIZE]: out[(t*B + m)*NSIZE + n] = bf16(acc + bias)
// Epilogue: per-wave LDS repack (XOR swizzle col^=(row&7)<<3) -> dwordx4 stores
// (round-6 epilogue was 128 scalar 2B stores/thread -> WRITE_SIZE +73MB amplification).
template<int NSIZE>
__global__ __launch_bounds__(512, 1) void gemm256(
    const unsigned short* __restrict__ A,
    const unsigned short* __restrict__ Bt,
    const float* __restrict__ bias,
    unsigned short* __restrict__ out_bf)
{
    constexpr int BK  = 64;
    constexpr int NBX = NSIZE / 256;   // 12 (qkv) or 4 (proj)
    constexpr int NBY = B_SZ / 256;    // 16
    constexpr int NWG = NBX * NBY * T_SZ;   // 768 / 256, both % 8 == 0

    __shared__ __align__(16) unsigned short lds[65536];   // 128 KiB
    // A buf0 [0,16384) buf1 [16384,32768); B buf0 [32768,49152) buf1 [49152,65536)

    // XCD-aware swizzle (T1)
    const int bid = blockIdx.x;
    const int swz = (bid & 7) * (NWG >> 3) + (bid >> 3);
    const int by  = swz & (NBY - 1);
    const int tmp = swz >> 4;
    const int bx  = tmp % NBX;
    const int t   = tmp / NBX;
    const int m0  = by * 256;
    const int n0  = bx * 256;

    const int tid  = threadIdx.x;
    const int lane = tid & 63;
    const int w    = tid >> 6;
    const int wm   = w >> 2;        // 0..1: which 128-row A half
    const int wn   = w & 3;         // 0..3: which 64-col B slice
    const int quad = lane >> 4;
    const int l16  = lane & 15;

    // staging slot precompute: slot q -> row q>>3, stored chunk q&7,
    // fetched data chunk = (q&7)^(row&7)  (inverse-swizzled global source)
    const int q0  = w * 128 + lane;
    const int q1  = q0 + 64;
    const int r0  = q0 >> 3, ch0 = (q0 & 7) ^ (r0 & 7);
    const int r1  = q1 >> 3, ch1 = (q1 & 7) ^ (r1 & 7);
    const unsigned short* Abase = A + (size_t)t * B_SZ * C_SZ;
    const unsigned short* Bbase = Bt + (size_t)t * NSIZE * C_SZ;
    const unsigned short* gA0 = Abase + (size_t)(m0 + r0) * C_SZ + ch0 * 8;
    const unsigned short* gA1 = Abase + (size_t)(m0 + r1) * C_SZ + ch1 * 8;
    const unsigned short* gB0 = Bbase + (size_t)(n0 + r0) * C_SZ + ch0 * 8;
    const unsigned short* gB1 = Bbase + (size_t)(n0 + r1) * C_SZ + ch1 * 8;
    unsigned short* dA0 = &lds[(w * 2 + 0) * 512];          // wave-uniform bases
    unsigned short* dA1 = &lds[(w * 2 + 1) * 512];
    unsigned short* dB0 = &lds[32768 + (w * 2 + 0) * 512];
    unsigned short* dB1 = &lds[32768 + (w * 2 + 1) * 512];

#define STG_A(buf, h, kt) do { \
    async16(gA0 + (size_t)(h) * 128 * C_SZ + (kt) * BK, dA0 + (buf) * 16384 + (h) * 8192); \
    async16(gA1 + (size_t)(h) * 128 * C_SZ + (kt) * BK, dA1 + (buf) * 16384 + (h) * 8192); \
} while (0)
#define STG_B(buf, h, kt) do { \
    async16(gB0 + (size_t)(h) * 128 * C_SZ + (kt) * BK, dB0 + (buf) * 16384 + (h) * 8192); \
    async16(gB1 + (size_t)(h) * 128 * C_SZ + (kt) * BK, dB1 + (buf) * 16384 + (h) * 8192); \
} while (0)

    // fragment read bases; chunk swizzle: stored = (ks*4+quad) ^ (l16&7)
    const int s7   = l16 & 7;
    const int swk0 = ((0 * 4 + quad) ^ s7) * 8;
    const int swk1 = ((1 * 4 + quad) ^ s7) * 8;
    const unsigned short* aR = &lds[wm * 8192 + l16 * 64];
    const unsigned short* bR = &lds[32768 + (wn >> 1) * 8192 + ((wn & 1) * 64 + l16) * 64];

#define LD_A(buf, mh) do { \
    _Pragma("unroll") \
    for (int mi = 0; mi < 4; ++mi) { \
        af[mi][0] = *(const s16x8*)(aR + (buf) * 16384 + ((mh) * 4 + mi) * 1024 + swk0); \
        af[mi][1] = *(const s16x8*)(aR + (buf) * 16384 + ((mh) * 4 + mi) * 1024 + swk1); \
    } \
} while (0)
#define LD_B(buf, nh, dst) do { \
    _Pragma("unroll") \
    for (int ni = 0; ni < 2; ++ni) { \
        dst[ni][0] = *(const s16x8*)(bR + (buf) * 16384 + ((nh) * 2 + ni) * 1024 + swk0); \
        dst[ni][1] = *(const s16x8*)(bR + (buf) * 16384 + ((nh) * 2 + ni) * 1024 + swk1); \
    } \
} while (0)
#define MM(mh, nh, bsrc) do { \
    _Pragma("unroll") \
    for (int mi = 0; mi < 4; ++mi) \
    _Pragma("unroll") \
    for (int ni = 0; ni < 2; ++ni) { \
        acc[(mh) * 4 + mi][(nh) * 2 + ni] = __builtin_amdgcn_mfma_f32_16x16x32_bf16( \
            af[mi][0], bsrc[ni][0], acc[(mh) * 4 + mi][(nh) * 2 + ni], 0, 0, 0); \
        acc[(mh) * 4 + mi][(nh) * 2 + ni] = __builtin_amdgcn_mfma_f32_16x16x32_bf16( \
            af[mi][1], bsrc[ni][1], acc[(mh) * 4 + mi][(nh) * 2 + ni], 0, 0, 0); \
    } \
} while (0)
#define WALL() do { \
    __builtin_amdgcn_s_barrier(); \
    __builtin_amdgcn_sched_barrier(0); \
} while (0)
#define KTILE(buf, kt, SP0, SP23, VMC) do { \
    /* region A */ \
    asm volatile("s_waitcnt vmcnt(" #VMC ")"); \
    __builtin_amdgcn_sched_barrier(0); \
    WALL(); \
    LD_B(buf, 0, bq0); \
    LD_A(buf, 0); \
    LD_B(buf, 1, bq1); \
    if (SP0) STG_A((buf) ^ 1, 1, (kt) + 1); \
    __builtin_amdgcn_s_setprio(1); MM(0, 0, bq0); MM(0, 1, bq1); __builtin_amdgcn_s_setprio(0); \
    /* region B */ \
    WALL(); \
    LD_A(buf, 1); \
    if (SP23) { STG_B(buf, 0, (kt) + 2); STG_A(buf, 0, (kt) + 2); STG_B(buf, 1, (kt) + 2); } \
    __builtin_amdgcn_s_setprio(1); MM(1, 1, bq1); MM(1, 0, bq0); __builtin_amdgcn_s_setprio(0); \
} while (0)

    f32x4 acc[8][4] = {};
    s16x8 af[4][2], bq0[2][2], bq1[2][2];

    // prologue: queue (oldest->newest): tile0 {A0,B0,B1,A1}, tile1 {B0,A0,B1} = 14 in flight.
    // First KTILE's vmcnt(6) retires through A1(0) -> tile0 fully resident.
    STG_A(0, 0, 0); STG_B(0, 0, 0); STG_B(0, 1, 0);
    STG_A(0, 1, 0);
    STG_B(1, 0, 1); STG_A(1, 0, 1); STG_B(1, 1, 1);

#pragma clang loop unroll(disable)
    for (int it = 0; it < 7; ++it) {    // tiles 0..13: full staging
        int kt = it * 2;
        KTILE(0, kt,     1, 1, 6);
        KTILE(1, kt + 1, 1, 1, 6);
    }
    KTILE(0, 14, 1, 0, 6);              // stages only A1(15)
    KTILE(1, 15, 0, 0, 0);              // drain tile

#undef KTILE
#undef WALL
#undef MM
#undef LD_B
#undef LD_A
#undef STG_B
#undef STG_A

    // ---- Epilogue via per-wave LDS repack ----
    // C/D layout: col = lane&15, row = quad*4 + reg  [verified m89/m91]
    // Wave region: 16 KiB at lds + w*8192 (ushort). Store idx = row*64 + (col ^ ((row&7)<<3)).
    // Read-back: lane reads STORED chunk (lane&7) of row -> linear LDS addr (conflict-free);
    // its DATA chunk is (lane&7)^(row&7) -> global col base; permutation of aligned 16B
    // chunks within each 128B row segment -> stores stay fully coalesced.
    __syncthreads();    // cross-wave WAR: LDS K-buffers -> epilogue regions
    unsigned short* ep = &lds[w * 8192];
#pragma unroll
    for (int ni = 0; ni < 4; ++ni) {
        int colb = ni * 16 + l16;
        float bi = bias[t * NSIZE + n0 + wn * 64 + colb];
#pragma unroll
        for (int mi = 0; mi < 8; ++mi) {
#pragma unroll
            for (int r = 0; r < 4; ++r) {
                int row = mi * 16 + quad * 4 + r;
                ep[row * 64 + (colb ^ ((row & 7) << 3))] = f2bf(acc[mi][ni][r] + bi);
            }
        }
    }
    // no barrier needed: wave reads only its own region (in-wave LDS dep, compiler waits)
    const int lr = lane >> 3, lc = lane & 7;
#pragma unroll
    for (int j = 0; j < 16; ++j) {
        int row = j * 8 + lr;
        s16x8 v = *reinterpret_cast<const s16x8*>(ep + row * 64 + lc * 8);
        int cdat = (lc ^ (row & 7)) * 8;
        int gm = m0 + wm * 128 + row;
        size_t o = ((size_t)t * B_SZ + gm) * NSIZE + (n0 + wn * 64 + cdat);
        *reinterpret_cast<s16x8*>(out_bf + o) = v;
    }
}

// ---------------- cross-task attention: 16 lanes per (b,h), 8 dims/lane ----------------
// qkv: bf16 task-major [T][B][3C]; ctx: bf16 task-major [T][B][C]
__global__ __launch_bounds__(256) void attn_kernel(const unsigned short* __restrict__ qkv,
                                                   unsigned short* __restrict__ ctx) {
    const int tid = threadIdx.x;
    const int li  = tid & 15;
    const int g   = blockIdx.x * 16 + (tid >> 4);   // [0, B*H)
    const int b   = g >> 3, h = g & 7;
    const int d0  = li * 8;

    float qf[4][8], kf[4][8], vf[4][8];
#pragma unroll
    for (int i = 0; i < 4; i++) {
        const unsigned short* p = qkv + (size_t)i * B_SZ * NQKV + (size_t)b * NQKV + h * DH_SZ + d0;
        s16x8 qv = *reinterpret_cast<const s16x8*>(p);
        s16x8 kv = *reinterpret_cast<const s16x8*>(p + C_SZ);
        s16x8 vv = *reinterpret_cast<const s16x8*>(p + 2 * C_SZ);
#pragma unroll
        for (int e = 0; e < 8; e++) {
            qf[i][e] = bf2f((unsigned short)qv[e]);
            kf[i][e] = bf2f((unsigned short)kv[e]);
            vf[i][e] = bf2f((unsigned short)vv[e]);
        }
    }
    float s[4][4];
#pragma unroll
    for (int i = 0; i < 4; i++)
#pragma unroll
        for (int j = 0; j < 4; j++) {
            float p = 0.0f;
#pragma unroll
            for (int e = 0; e < 8; e++) p += qf[i][e] * kf[j][e];
            p += __shfl_xor(p, 8);
            p += __shfl_xor(p, 4);
            p += __shfl_xor(p, 2);
            p += __shfl_xor(p, 1);
            s[i][j] = p * SCALE_F;
        }
#pragma unroll
    for (int i = 0; i < 4; i++) {
        float m = fmaxf(fmaxf(s[i][0], s[i][1]), fmaxf(s[i][2], s[i][3]));
        float e0 = __expf(s[i][0] - m), e1 = __expf(s[i][1] - m);
        float e2 = __expf(s[i][2] - m), e3 = __expf(s[i][3] - m);
        float inv = 1.0f / (e0 + e1 + e2 + e3);
        s[i][0] = e0 * inv; s[i][1] = e1 * inv; s[i][2] = e2 * inv; s[i][3] = e3 * inv;
    }
#pragma unroll
    for (int i = 0; i < 4; i++) {
        s16x8 ov;
#pragma unroll
        for (int e = 0; e < 8; e++) {
            float o = s[i][0] * vf[0][e] + s[i][1] * vf[1][e]
                    + s[i][2] * vf[2][e] + s[i][3] * vf[3][e];
            ov[e] = (short)f2bf(o);
        }
        *reinterpret_cast<s16x8*>(ctx + (size_t)i * B_SZ * C_SZ + (size_t)b * C_SZ + h * DH_SZ + d0) = ov;
    }
}

// ---------------- fused residual + LayerNorm: wave per row, 4 rows/block ----------------
// yb: bf16 task-major [T][B][C]; feats/out: fp32 [B][T][C] (row r = b*T + t)
__global__ __launch_bounds__(256) void ln_fused(const unsigned short* __restrict__ yb,
                                                const float* __restrict__ feats,
                                                const float* __restrict__ gamma,
                                                const float* __restrict__ beta,
                                                float* __restrict__ out) {
    const int wave = threadIdx.x >> 6, lane = threadIdx.x & 63;
    const int row = blockIdx.x * 4 + wave;          // row = b*T + t
    const unsigned short* yp = yb + ((size_t)(row & 3) * B_SZ + (row >> 2)) * C_SZ;
    const float* fp = feats + (size_t)row * C_SZ;

    float x[4][4];
    float s = 0.0f, ss = 0.0f;
#pragma unroll
    for (int c = 0; c < 4; c++) {
        int col = c * 256 + lane * 4;
        ushort4 u = *reinterpret_cast<const ushort4*>(yp + col);
        float4 f = *reinterpret_cast<const float4*>(fp + col);
        x[c][0] = bf2f(u.x) + f.x;
        x[c][1] = bf2f(u.y) + f.y;
        x[c][2] = bf2f(u.z) + f.z;
        x[c][3] = bf2f(u.w) + f.w;
#pragma unroll
        for (int j = 0; j < 4; j++) { s += x[c][j]; ss += x[c][j] * x[c][j]; }
    }
#pragma unroll
    for (int off = 32; off > 0; off >>= 1) { s += __shfl_xor(s, off); ss += __shfl_xor(ss, off); }
    float mean = s * (1.0f / C_SZ);
    float var  = ss * (1.0f / C_SZ) - mean * mean;
    float inv  = rsqrtf(var + 1e-5f);
#pragma unroll
    for (int c = 0; c < 4; c++) {
        int col = c * 256 + lane * 4;
        float4 g  = *reinterpret_cast<const float4*>(gamma + col);
        float4 be = *reinterpret_cast<const float4*>(beta + col);
        float4 o;
        o.x = (x[c][0] - mean) * inv * g.x + be.x;
        o.y = (x[c][1] - mean) * inv * g.y + be.y;
        o.z = (x[c][2] - mean) * inv * g.z + be.z;
        o.w = (x[c][3] - mean) * inv * g.w + be.w;
        *reinterpret_cast<float4*>(out + (size_t)row * C_SZ + col) = o;
    }
}

extern "C" void kernel_launch(void* const* d_in, const int* in_sizes, int n_in,
                              void* d_out, int out_size, void* d_ws, size_t ws_size,
                              hipStream_t stream) {
    const float* feats = (const float*)d_in[0];   // [B,T,C]
    const float* Wqkv  = (const float*)d_in[1];   // [T,C,3C]
    const float* bqkv  = (const float*)d_in[2];   // [T,3C]
    const float* Wproj = (const float*)d_in[3];   // [T,C,C]
    const float* bproj = (const float*)d_in[4];   // [T,C]
    const float* gamma = (const float*)d_in[5];   // [C]
    const float* beta  = (const float*)d_in[6];   // [C]
    float* out = (float*)d_out;

    // ws layout (bytes):
    //   [0,   33.5M)  featsT bf16 [T,B,C]
    //   [33.5M, 58.7M) WqkvT bf16 [T,3C,C]
    //   [58.7M, 67.1M) WprojT bf16 [T,C,C]
    //   [67.1M, 167.8M) qkvT bf16 [T,B,3C]   (later aliased by ybufT bf16 [T,B,C])
    //   [167.8M, 201.3M) ctxT bf16 [T,B,C]
    char* ws = (char*)d_ws;
    unsigned short* feats_bf = (unsigned short*)(ws);
    unsigned short* wqkv_t   = (unsigned short*)(ws + 33554432);
    unsigned short* wproj_t  = (unsigned short*)(ws + 58720256);
    unsigned short* qkv      = (unsigned short*)(ws + 67108864);
    unsigned short* ctx      = (unsigned short*)(ws + 167772160);
    unsigned short* ybuf_bf  = (unsigned short*)(ws + 67108864);  // aliases qkv (dead after attn)

    // merged prep: 6144 (Wqkv-T) + 2048 (Wproj-T) + 4096 (feats permute+cvt)
    prep_kernel<<<12288, 256, 0, stream>>>(Wqkv, Wproj, feats, wqkv_t, wproj_t, feats_bf);

    // QKV: grid = (3072/256)*(4096/256)*4 = 768 blocks of 512
    gemm256<NQKV><<<dim3(768), 512, 0, stream>>>(feats_bf, wqkv_t, bqkv, qkv);

    attn_kernel<<<(B_SZ * H_SZ) / 16, 256, 0, stream>>>(qkv, ctx);

    // proj: grid = (1024/256)*(4096/256)*4 = 256 blocks of 512
    gemm256<C_SZ><<<dim3(256), 512, 0, stream>>>(ctx, wproj_t, bproj, ybuf_bf);

    // fused residual + LN (wave per row)
    ln_fused<<<(B_SZ * T_SZ) / 4, 256, 0, stream>>>(ybuf_bf, feats, gamma, beta, out);
}